// Round 4
// baseline (1358.603 us; speedup 1.0000x reference)
//
#include <hip/hip_runtime.h>
#include <hip/hip_bf16.h>

// CGCNN forward, MFMA conv GEMM (R12).
//   g[e,:] = [x[n(e)] | x[nb(e)] | bond(e)] @ Wf + b  (K=169 pad 192, N=128)
// R12 vs R11: every attempt to hold prefetched data live across the MFMA
// phase spilled (R9 59MB, R10 279MB, R11 162MB scratch writes) because the
// per-wave live-set (Bf=48 + frags) exceeds the compiler's ~80-130 VGPR
// comfort zone. R12 shrinks the live-set structurally:
//   - 8 waves/block (512 thr), ONE 16-col N-tile per wave -> B frags = 24
//     VGPRs (was 48).
//   - fully-unrolled 15-group (5 supertiles x 3 et) rolling pipeline with
//     two named frag sets FA/FB (static indexing, no scratch), loads issued
//     2 groups ahead of use; sched_barrier(0) pins issue order.
//   - 15 nbr indices prefetched in the prologue (removes idx latency).
//   - launch_bounds(512,4): VGPR cap 128 >= ~117 live-set -> no spill,
//     4 waves/SIMD occupancy (2x R8).
//   - stats pass: ZERO barriers. ACT pass: raw lgkm-only barriers (R11
//     verified pattern), p-combine across wave halves via 1KB pbuf.
// Canary: stats WRITE_SIZE must be ~1MB (no spill). bond_prep back to R8
// row-major layout (matches direct per-lane loads, R8-verified).
// R7 LDS-staging fallback kept for ws_size < 108.5 MB.

#define NATOM 60000
#define MNBR  12
#define F0D   92
#define FBD   41
#define FD    64
#define F2D   128
#define NCRY  2000
#define HD    128
#define NSUP  15000          // 720000 edges / 48
#define GS    132            // gbuf row stride (floats)
#define CGRID 3000           // conv grid; NSUP/CGRID == 5 exactly

// ws layout (float units)
#define OFF_X      0ull          // 3,840,000 f32
#define OFF_XH     3840000ull    // 3,840,000 u16
#define OFF_SUMMED 5760000ull    // 3,840,000 f32
#define OFF_STATS  9600000ull    // sum1[128] sq1[128] sum2[64] sq2[64]
#define OFF_CRYS   9600384ull
#define OFF_CNT    9728384ull
#define OFF_WCONV  9730384ull    // 80,833 f32
#define OFF_WBF    9811220ull    // 73,728 u16 = 36,864 f slots
#define OFF_FLAG   9848084ull
#define WS_NEED_BYTES (9848085ull * 4ull)
#define OFF_BPAD   9848088ull    // 34,560,000 u16 = 17,280,000 f slots (16B aligned)
#define WS_FULL_BYTES ((OFF_BPAD + 17280000ull) * 4ull)   // 108,512,352

// offsets inside wconv
#define W_EMB_O  0
#define B_EMB_O  5888
#define W_FULL_O 5952
#define B_FULL_O 70848
#define G1_O     71232
#define BE1_O    71616
#define G2_O     72000
#define BE2_O    72192
#define W_FC_O   72384
#define B_FC_O   80576
#define W_OUT_O  80704
#define B_OUT_O  80832
#define WC_TOTAL 80833

typedef unsigned short u16;
typedef __attribute__((ext_vector_type(8))) short bf16x8;
typedef __attribute__((ext_vector_type(4))) float f32x4;

__device__ __forceinline__ float bf2f(u16 u){
  union { unsigned int i; float f; } v; v.i = ((unsigned int)u) << 16; return v.f;
}
__device__ __forceinline__ u16 f2bf(float f){
  union { float f; unsigned int i; } v; v.f = f;
  unsigned int x = v.i;
  return (u16)((x + 0x7FFFu + ((x >> 16) & 1u)) >> 16);
}
__device__ __forceinline__ float softplusf_(float x){
  return fmaxf(x, 0.f) + log1pf(expf(-fabsf(x)));
}
__device__ __forceinline__ float softplus_fast(float x){
  return fmaxf(x, 0.f) + __logf(1.f + __expf(-fabsf(x)));
}
__device__ __forceinline__ float sigmoid_fast(float x){
  return __builtin_amdgcn_rcpf(1.f + __expf(-x));
}

__global__ __launch_bounds__(64) void detect_kernel(
    const u16* __restrict__ data, int* __restrict__ flag){
  int tid = threadIdx.x;
  float v = bf2f(data[tid * 2]);
  float av = fabsf(v);
  bool sane = (av > 1e-6f) && (av < 100.f);
  unsigned long long m = __ballot(sane);
  if (tid == 0) *flag = (__popcll(m) >= 32) ? 1 : 0;
}

struct CvtArgs {
  const void* src[12];
  int start[13];
};

__global__ __launch_bounds__(256) void cvt_all_kernel(
    CvtArgs a, float* __restrict__ dst, const int* __restrict__ flag){
  int i = blockIdx.x * 256 + threadIdx.x;
  if (i >= WC_TOTAL) return;
  int r = 0;
  while (i >= a.start[r + 1]) r++;
  int rel = i - a.start[r];
  if (*flag) dst[i] = bf2f(((const u16*)a.src[r])[rel]);
  else       dst[i] = ((const float*)a.src[r])[rel];
}

__global__ __launch_bounds__(256) void build_bfrag(
    const float* __restrict__ wfull, u16* __restrict__ wbf){
  int t = blockIdx.x * 256 + threadIdx.x;
  if (t >= 3 * 6 * 8 * 64) return;
  int lane = t & 63, nt = (t >> 6) & 7, c = (t >> 9) % 6, layer = t / 3072;
  int q = lane >> 4, nloc = lane & 15;
  u16 vals[8];
  #pragma unroll
  for (int i = 0; i < 8; i++){
    int k = c * 32 + q * 8 + i;
    float v = (k < 169) ? wfull[layer * 169 * F2D + k * F2D + nt * 16 + nloc] : 0.f;
    vals[i] = f2bf(v);
  }
  *(uint4*)&wbf[(size_t)t * 8] = *(uint4*)vals;
}

// One-time repack ROW-MAJOR (R8-verified): bond_pad[e][0..47] = bf16(bond),
// zero for k>=41. Matches conv's direct per-lane b128 loads.
__global__ __launch_bounds__(256) void bond_prep(
    const void* __restrict__ nbr_fea, u16* __restrict__ bond_pad,
    const int* __restrict__ flag){
  __shared__ __align__(16) char sm[7872];
  u16*   lb_u = (u16*)sm;
  float* lb_f = (float*)sm;
  int s = blockIdx.x, tid = threadIdx.x;
  const int isbf = *flag;
  if (isbf){
    const uint4* src = (const uint4*)((const u16*)nbr_fea + (size_t)s * 1968);
    if (tid < 246) ((uint4*)sm)[tid] = src[tid];
  } else {
    const uint4* src = (const uint4*)((const float*)nbr_fea + (size_t)s * 1968);
    for (int t = tid; t < 492; t += 256) ((uint4*)sm)[t] = src[t];
  }
  __syncthreads();
  uint4* outv = (uint4*)(bond_pad + (size_t)s * 2304);
  for (int slot = tid; slot < 288; slot += 256){
    int el = slot / 6, jj = slot - el * 6;
    u16 v[8];
    #pragma unroll
    for (int i = 0; i < 8; i++){
      int k = jj * 8 + i;
      v[i] = (k < FBD) ? (isbf ? lb_u[el * FBD + k] : f2bf(lb_f[el * FBD + k])) : (u16)0;
    }
    outv[slot] = *(uint4*)v;
  }
}

__global__ __launch_bounds__(256) void embed_kernel(
    const void* __restrict__ atom_fea, const float* __restrict__ W_emb,
    const float* __restrict__ b_emb, float* __restrict__ x,
    u16* __restrict__ xh, const int* __restrict__ flag){
  int tid = threadIdx.x;
  int n = blockIdx.x * 4 + (tid >> 6);
  int f = tid & 63;
  float acc = b_emb[f];
  if (*flag){
    const u16* arow = (const u16*)atom_fea + n * F0D;
    for (int k = 0; k < F0D; k++)
      acc = fmaf(bf2f(arow[k]), W_emb[k * FD + f], acc);
  } else {
    const float* arow = (const float*)atom_fea + n * F0D;
    for (int k = 0; k < F0D; k++)
      acc = fmaf(arow[k], W_emb[k * FD + f], acc);
  }
  x[n * FD + f] = acc;
  xh[n * FD + f] = f2bf(acc);
}

// ---------------------------------------------------------------------------
// R12: 8-wave pipelined conv pass. Wave wv (0..7) owns N-tile cols
// wv*16..wv*16+15. 15 groups (5 supertiles x 3 et-subtiles of 16 edges),
// fully unrolled, rolling 2-set (FA/FB) register pipeline.
// ---------------------------------------------------------------------------
template<int ACT>
__global__ __launch_bounds__(512, 4) void conv_pipe8(
    const u16* __restrict__ xh, const u16* __restrict__ bond_pad,
    const int* __restrict__ nbr_idx, const u16* __restrict__ wbf_l,
    const float* __restrict__ bfull, const float* __restrict__ sum1,
    const float* __restrict__ sq1, const float* __restrict__ g1,
    const float* __restrict__ be1, float* __restrict__ summed,
    float* __restrict__ o_sum, float* __restrict__ o_sq){
  extern __shared__ char smem[];
  float* gbuf = (float*)smem;                 // ACT: 48*GS f32
  float* pbuf = gbuf + 48 * GS;               // ACT: 4*64 f32
  float* redS = ACT ? (pbuf + 4 * 64) : (float*)smem;
  float* redQ = redS + (ACT ? 64 : 128);

  const int tid = threadIdx.x;
  const int wv = tid >> 6;                    // n-tile 0..7
  const int lane = tid & 63, q = lane >> 4, nloc = lane & 15;

  bf16x8 Bf[6];
  const bf16x8* Bv = (const bf16x8*)wbf_l;
  #pragma unroll
  for (int c = 0; c < 6; c++) Bf[c] = Bv[(c * 8 + wv) * 64 + lane];
  const float bias = bfull[wv * 16 + nloc];

  float A0 = 0.f, B0 = 0.f, A1 = 0.f, B1 = 0.f;
  if (ACT){
    const int cl = tid & 63;
    const float invR = 1.f / (float)(NATOM * MNBR);
    float m0 = sum1[cl] * invR;
    float v0 = fmaxf(sq1[cl] * invR - m0 * m0, 0.f);
    A0 = g1[cl] * rsqrtf(v0 + 1e-5f);  B0 = be1[cl] - m0 * A0;
    float m1 = sum1[64 + cl] * invR;
    float v1 = fmaxf(sq1[64 + cl] * invR - m1 * m1, 0.f);
    A1 = g1[64 + cl] * rsqrtf(v1 + 1e-5f);  B1 = be1[64 + cl] - m1 * A1;
  }
  float sAcc = 0.f, qAcc = 0.f;
  if (tid < (ACT ? 64 : 128)){ redS[tid] = 0.f; redQ[tid] = 0.f; }

  const bf16x8* xv = (const bf16x8*)xh;
  const char* bpad8 = (const char*)bond_pad;
  const bf16x8 zero8 = {0,0,0,0,0,0,0,0};
  const int s0 = blockIdx.x;

  // prologue: all 15 nbr indices in flight at once (per-lane)
  int nb[15];
  #pragma unroll
  for (int k = 0; k < 5; k++)
    #pragma unroll
    for (int et = 0; et < 3; et++)
      nb[k * 3 + et] = nbr_idx[(s0 + k * CGRID) * 48 + et * 16 + nloc];

  bf16x8 FA0, FA1, FA2, FA3, FA4, FA5;
  bf16x8 FB0, FB1, FB2, FB3, FB4, FB5;

#define LOADG(P, g_) {                                                          \
    const int k_ = (g_) / 3, et_ = (g_) % 3;                                    \
    const int ss_ = s0 + k_ * CGRID;                                            \
    const int na_ = ss_ * 4 + (et_ * 16 + nloc) / 12;                           \
    const int nb_ = nb[(g_)];                                                   \
    P##0 = xv[(size_t)na_ * 8 + q];                                             \
    P##1 = xv[(size_t)na_ * 8 + 4 + q];                                         \
    P##2 = xv[(size_t)nb_ * 8 + q];                                             \
    P##3 = xv[(size_t)nb_ * 8 + 4 + q];                                         \
    const bf16x8* bp_ = (const bf16x8*)(bpad8 +                                 \
        ((size_t)ss_ * 48 + et_ * 16 + nloc) * 96);                             \
    P##4 = bp_[q];                                                              \
    P##5 = (q < 2) ? bp_[4 + q] : zero8;                                        \
  }

#define MFMAG(P, g_) {                                                          \
    const int et_ = (g_) % 3;                                                   \
    f32x4 acc = {bias, bias, bias, bias};                                       \
    acc = __builtin_amdgcn_mfma_f32_16x16x32_bf16(P##4, Bf[4], acc, 0, 0, 0);   \
    acc = __builtin_amdgcn_mfma_f32_16x16x32_bf16(P##5, Bf[5], acc, 0, 0, 0);   \
    acc = __builtin_amdgcn_mfma_f32_16x16x32_bf16(P##0, Bf[0], acc, 0, 0, 0);   \
    acc = __builtin_amdgcn_mfma_f32_16x16x32_bf16(P##1, Bf[1], acc, 0, 0, 0);   \
    acc = __builtin_amdgcn_mfma_f32_16x16x32_bf16(P##2, Bf[2], acc, 0, 0, 0);   \
    acc = __builtin_amdgcn_mfma_f32_16x16x32_bf16(P##3, Bf[3], acc, 0, 0, 0);   \
    if (ACT){                                                                   \
      const int col_ = wv * 16 + nloc;                                          \
      const int r0_ = et_ * 16 + q * 4;                                         \
      gbuf[(r0_ + 0) * GS + col_] = acc[0];                                     \
      gbuf[(r0_ + 1) * GS + col_] = acc[1];                                     \
      gbuf[(r0_ + 2) * GS + col_] = acc[2];                                     \
      gbuf[(r0_ + 3) * GS + col_] = acc[3];                                     \
    } else {                                                                    \
      sAcc += acc[0] + acc[1] + acc[2] + acc[3];                                \
      qAcc += acc[0]*acc[0] + acc[1]*acc[1] + acc[2]*acc[2] + acc[3]*acc[3];    \
    }                                                                           \
  }

// step: consume group g from set P, refill P with group g+2, pin order
#define STEP(P, g_) { MFMAG(P, g_); LOADG(P, (g_) + 2);                         \
    __builtin_amdgcn_sched_barrier(0); }
#define STEPL(P, g_) { MFMAG(P, g_); __builtin_amdgcn_sched_barrier(0); }

// ACT phase for supertile k: two raw lgkm-only barriers (global prefetch for
// the next groups stays in flight underneath).
#define ACTPH(k_) if (ACT){                                                     \
    __builtin_amdgcn_sched_barrier(0);                                          \
    asm volatile("s_waitcnt lgkmcnt(0)");                                       \
    __builtin_amdgcn_s_barrier();                                               \
    __builtin_amdgcn_sched_barrier(0);                                          \
    const int cl_ = tid & 63, a_ = tid >> 7, h_ = (tid >> 6) & 1;               \
    float ph = 0.f;                                                             \
    _Pragma("unroll")                                                           \
    for (int m = 0; m < 6; m++){                                                \
      int el = a_ * 12 + h_ * 6 + m;                                            \
      float u = fmaf(gbuf[el * GS + cl_],      A0, B0);                         \
      float v = fmaf(gbuf[el * GS + 64 + cl_], A1, B1);                         \
      ph = fmaf(sigmoid_fast(u), softplus_fast(v), ph);                         \
    }                                                                           \
    if (h_) pbuf[a_ * 64 + cl_] = ph;                                           \
    __builtin_amdgcn_sched_barrier(0);                                          \
    asm volatile("s_waitcnt lgkmcnt(0)");                                       \
    __builtin_amdgcn_s_barrier();                                               \
    __builtin_amdgcn_sched_barrier(0);                                          \
    if (!h_){                                                                   \
      float p = ph + pbuf[a_ * 64 + cl_];                                       \
      summed[((size_t)(s0 + (k_) * CGRID) * 4 + a_) * 64 + cl_] = p;            \
      sAcc += p;  qAcc = fmaf(p, p, qAcc);                                      \
    }                                                                           \
  }

  LOADG(FA, 0);
  LOADG(FB, 1);
  __builtin_amdgcn_sched_barrier(0);

  // k=0
  STEP(FA, 0);  STEP(FB, 1);  STEP(FA, 2);   ACTPH(0);
  // k=1
  STEP(FB, 3);  STEP(FA, 4);  STEP(FB, 5);   ACTPH(1);
  // k=2
  STEP(FA, 6);  STEP(FB, 7);  STEP(FA, 8);   ACTPH(2);
  // k=3
  STEP(FB, 9);  STEP(FA, 10); STEP(FB, 11);  ACTPH(3);
  // k=4
  STEP(FA, 12); STEPL(FB, 13); STEPL(FA, 14); ACTPH(4);

#undef LOADG
#undef MFMAG
#undef STEP
#undef STEPL
#undef ACTPH

  __syncthreads();
  if (ACT){
    if (!((tid >> 6) & 1)){
      atomicAdd(&redS[tid & 63], sAcc);
      atomicAdd(&redQ[tid & 63], qAcc);
    }
    __syncthreads();
    if (tid < 64){ atomicAdd(&o_sum[tid], redS[tid]); atomicAdd(&o_sq[tid], redQ[tid]); }
  } else {
    int c0 = wv * 16 + nloc;
    atomicAdd(&redS[c0], sAcc);
    atomicAdd(&redQ[c0], qAcc);
    __syncthreads();
    if (tid < 128){ atomicAdd(&o_sum[tid], redS[tid]); atomicAdd(&o_sq[tid], redQ[tid]); }
  }
}

// R7 fallback conv pass (small-ws path; reads raw nbr_fea, no bond_pad).
template<int ACT>
__global__ __launch_bounds__(256, 3) void conv_mfma(
    const u16* __restrict__ xh, const void* __restrict__ nbr_fea,
    const int* __restrict__ nbr_idx, const u16* __restrict__ wbf_l,
    const float* __restrict__ bfull, const float* __restrict__ sum1,
    const float* __restrict__ sq1, const float* __restrict__ g1,
    const float* __restrict__ be1, float* __restrict__ summed,
    float* __restrict__ o_sum, float* __restrict__ o_sq,
    const int* __restrict__ flag){
  extern __shared__ char smem[];
  u16*   fragA = (u16*)smem;                      // 6*512 u16
  float* gbuf  = (float*)(smem + 6144);           // ACT only: 48*GS
  float* redS  = ACT ? (gbuf + 48 * GS) : (float*)(smem + 6144);
  float* redQ  = redS + (ACT ? 64 : 128);

  const int tid = threadIdx.x;
  const int w = tid >> 6, lane = tid & 63;
  const int q = lane >> 4, nloc = lane & 15, q8 = q * 8;
  const int isbf = *flag;

  bf16x8 Bf[6][2];
  const bf16x8* Bv = (const bf16x8*)wbf_l;
  #pragma unroll
  for (int c = 0; c < 6; c++)
    #pragma unroll
    for (int t2 = 0; t2 < 2; t2++)
      Bf[c][t2] = Bv[(c * 8 + w * 2 + t2) * 64 + lane];
  float bias0 = bfull[w * 32 + nloc];
  float bias1 = bfull[w * 32 + 16 + nloc];

  float A0 = 0.f, B0 = 0.f, A1 = 0.f, B1 = 0.f;
  if (ACT){
    const float invR = 1.f / (float)(NATOM * MNBR);
    float m0 = sum1[lane] * invR;
    float v0 = fmaxf(sq1[lane] * invR - m0 * m0, 0.f);
    A0 = g1[lane] * rsqrtf(v0 + 1e-5f);  B0 = be1[lane] - m0 * A0;
    float m1 = sum1[64 + lane] * invR;
    float v1 = fmaxf(sq1[64 + lane] * invR - m1 * m1, 0.f);
    A1 = g1[64 + lane] * rsqrtf(v1 + 1e-5f);  B1 = be1[64 + lane] - m1 * A1;
  }
  float sAcc0 = 0.f, sAcc1 = 0.f, qAcc0 = 0.f, qAcc1 = 0.f;
  if (tid < (ACT ? 64 : 128)){ redS[tid] = 0.f; redQ[tid] = 0.f; }

  const bf16x8* xv = (const bf16x8*)xh;
  for (int s = blockIdx.x; s < NSUP; s += gridDim.x){
    int e0 = s * 48 + nloc;
    int nb0 = nbr_idx[e0], nb1 = nbr_idx[e0 + 16], nb2 = nbr_idx[e0 + 32];
    bf16x8 Af[3][6];
    if (w < 3){
      size_t eg = (size_t)(s * 48 + w * 16 + nloc);
      u16 v4[8], v5[8];
      if (isbf){
        const u16* br = (const u16*)nbr_fea + eg * 41;
        #pragma unroll
        for (int i = 0; i < 8; i++) v4[i] = br[q8 + i];
        #pragma unroll
        for (int i = 0; i < 8; i++){
          int k5 = 32 + q8 + i;
          v5[i] = (k5 < 41) ? br[k5] : (u16)0;
        }
      } else {
        const float* br = (const float*)nbr_fea + eg * 41;
        #pragma unroll
        for (int i = 0; i < 8; i++) v4[i] = f2bf(br[q8 + i]);
        #pragma unroll
        for (int i = 0; i < 8; i++){
          int k5 = 32 + q8 + i;
          v5[i] = (k5 < 41) ? f2bf(br[k5]) : (u16)0;
        }
      }
      *(uint4*)&fragA[(w * 2 + 0) * 512 + lane * 8] = *(uint4*)v4;
      *(uint4*)&fragA[(w * 2 + 1) * 512 + lane * 8] = *(uint4*)v5;
    }
    __syncthreads();
    #pragma unroll
    for (int et = 0; et < 3; et++){
      int nb = (et == 0) ? nb0 : (et == 1) ? nb1 : nb2;
      int na = s * 4 + (et * 16 + nloc) / 12;
      Af[et][0] = xv[na * 8 + q];
      Af[et][1] = xv[na * 8 + 4 + q];
      Af[et][2] = xv[nb * 8 + q];
      Af[et][3] = xv[nb * 8 + 4 + q];
      Af[et][4] = *(bf16x8*)&fragA[(et * 2 + 0) * 512 + lane * 8];
      Af[et][5] = *(bf16x8*)&fragA[(et * 2 + 1) * 512 + lane * 8];
    }
    #pragma unroll
    for (int et = 0; et < 3; et++){
      #pragma unroll
      for (int t2 = 0; t2 < 2; t2++){
        float bs = t2 ? bias1 : bias0;
        f32x4 acc = {bs, bs, bs, bs};
        acc = __builtin_amdgcn_mfma_f32_16x16x32_bf16(Af[et][0], Bf[0][t2], acc, 0, 0, 0);
        acc = __builtin_amdgcn_mfma_f32_16x16x32_bf16(Af[et][1], Bf[1][t2], acc, 0, 0, 0);
        acc = __builtin_amdgcn_mfma_f32_16x16x32_bf16(Af[et][2], Bf[2][t2], acc, 0, 0, 0);
        acc = __builtin_amdgcn_mfma_f32_16x16x32_bf16(Af[et][3], Bf[3][t2], acc, 0, 0, 0);
        acc = __builtin_amdgcn_mfma_f32_16x16x32_bf16(Af[et][4], Bf[4][t2], acc, 0, 0, 0);
        acc = __builtin_amdgcn_mfma_f32_16x16x32_bf16(Af[et][5], Bf[5][t2], acc, 0, 0, 0);
        if (ACT){
          int col = w * 32 + t2 * 16 + nloc;
          int r0 = et * 16 + q * 4;
          gbuf[(r0 + 0) * GS + col] = acc[0];
          gbuf[(r0 + 1) * GS + col] = acc[1];
          gbuf[(r0 + 2) * GS + col] = acc[2];
          gbuf[(r0 + 3) * GS + col] = acc[3];
        } else {
          float ss = acc[0] + acc[1] + acc[2] + acc[3];
          float qq = acc[0]*acc[0] + acc[1]*acc[1] + acc[2]*acc[2] + acc[3]*acc[3];
          if (t2){ sAcc1 += ss; qAcc1 += qq; } else { sAcc0 += ss; qAcc0 += qq; }
        }
      }
    }
    if (ACT){
      __syncthreads();
      float p = 0.f;
      #pragma unroll
      for (int m = 0; m < 12; m++){
        int el = w * 12 + m;
        float u = fmaf(gbuf[el * GS + lane],      A0, B0);
        float v = fmaf(gbuf[el * GS + 64 + lane], A1, B1);
        p = fmaf(sigmoid_fast(u), softplus_fast(v), p);
      }
      summed[(s * 4 + w) * 64 + lane] = p;
      sAcc0 += p;  qAcc0 = fmaf(p, p, qAcc0);
    }
    __syncthreads();
  }
  if (ACT){
    atomicAdd(&redS[lane], sAcc0);
    atomicAdd(&redQ[lane], qAcc0);
    __syncthreads();
    if (tid < 64){ atomicAdd(&o_sum[tid], redS[tid]); atomicAdd(&o_sq[tid], redQ[tid]); }
  } else {
    int c0 = w * 32 + nloc;
    atomicAdd(&redS[c0], sAcc0);       atomicAdd(&redQ[c0], qAcc0);
    atomicAdd(&redS[c0 + 16], sAcc1);  atomicAdd(&redQ[c0 + 16], qAcc1);
    __syncthreads();
    if (tid < 128){ atomicAdd(&o_sum[tid], redS[tid]); atomicAdd(&o_sq[tid], redQ[tid]); }
  }
}

__global__ __launch_bounds__(256) void update_x_kernel(
    float* __restrict__ x, u16* __restrict__ xh,
    const float* __restrict__ summed,
    const float* __restrict__ sum2, const float* __restrict__ sq2,
    const float* __restrict__ g2, const float* __restrict__ be2){
  int idx = blockIdx.x * 256 + threadIdx.x;
  int f = idx & 63;
  const float invN = 1.f / (float)NATOM;
  float mean = sum2[f] * invN;
  float var  = fmaxf(sq2[f] * invN - mean * mean, 0.f);
  float a = g2[f] * rsqrtf(var + 1e-5f);
  float b = be2[f] - mean * a;
  float v = x[idx] + fmaf(summed[idx], a, b);
  float r = softplusf_(v);
  x[idx] = r;
  xh[idx] = f2bf(r);
}

__global__ __launch_bounds__(256) void pool_kernel(
    const float* __restrict__ x, const int* __restrict__ cidx,
    float* __restrict__ crys, float* __restrict__ cnt){
  int idx = blockIdx.x * 256 + threadIdx.x;
  int n = idx >> 6, f = idx & 63;
  int c = cidx[n];
  atomicAdd(&crys[c * FD + f], x[idx]);
  if (f == 0) atomicAdd(&cnt[c], 1.f);
}

__global__ __launch_bounds__(128) void head_kernel(
    const float* __restrict__ crys, const float* __restrict__ cnt,
    const float* __restrict__ W_fc, const float* __restrict__ b_fc,
    const float* __restrict__ W_out, const float* __restrict__ b_out,
    void* __restrict__ out, const int* __restrict__ flag){
  __shared__ float p_s[FD];
  __shared__ float red_s[HD];
  int c = blockIdx.x, tid = threadIdx.x;
  if (tid < FD){
    float ct = fmaxf(cnt[c], 1.f);
    p_s[tid] = softplusf_(crys[c * FD + tid] / ct);
  }
  __syncthreads();
  float acc = b_fc[tid];
  for (int k = 0; k < FD; k++)
    acc = fmaf(p_s[k], W_fc[k * HD + tid], acc);
  float h = softplusf_(acc);
  red_s[tid] = h * W_out[tid];
  __syncthreads();
  for (int s = HD / 2; s > 0; s >>= 1){
    if (tid < s) red_s[tid] += red_s[tid + s];
    __syncthreads();
  }
  if (tid == 0){
    float r = red_s[0] + b_out[0];
    if (*flag) ((u16*)out)[c] = f2bf(r);
    else       ((float*)out)[c] = r;
  }
}

extern "C" void kernel_launch(void* const* d_in, const int* in_sizes, int n_in,
                              void* d_out, int out_size, void* d_ws, size_t ws_size,
                              hipStream_t stream){
  if (ws_size < WS_NEED_BYTES) return;  // diagnostic: leaves d_out zeroed
  const bool full = (ws_size >= WS_FULL_BYTES);
  const void* atom_fea = d_in[0];
  const void* nbr_fea  = d_in[1];
  const int* nbr_idx   = (const int*)d_in[2];
  const int* cidx      = (const int*)d_in[3];

  float* ws     = (float*)d_ws;
  float* x      = ws + OFF_X;
  u16*   xh     = (u16*)(ws + OFF_XH);
  float* summed = ws + OFF_SUMMED;
  float* sum1   = ws + OFF_STATS;
  float* sq1    = sum1 + 128;
  float* sum2   = sq1 + 128;
  float* sq2    = sum2 + 64;
  float* crys   = ws + OFF_CRYS;
  float* cnt    = ws + OFF_CNT;
  float* wc     = ws + OFF_WCONV;
  u16*   wbf    = (u16*)(ws + OFF_WBF);
  int*   flag   = (int*)(ws + OFF_FLAG);
  u16*   bpad   = (u16*)(ws + OFF_BPAD);

  detect_kernel<<<1, 64, 0, stream>>>((const u16*)nbr_fea, flag);
  CvtArgs ca;
  const int srcidx[12] = {4,5,6,7,8,9,10,11,12,13,14,15};
  const int starts[13] = {W_EMB_O, B_EMB_O, W_FULL_O, B_FULL_O, G1_O, BE1_O,
                          G2_O, BE2_O, W_FC_O, B_FC_O, W_OUT_O, B_OUT_O, WC_TOTAL};
  for (int i = 0; i < 12; i++){ ca.src[i] = d_in[srcidx[i]]; ca.start[i] = starts[i]; }
  ca.start[12] = WC_TOTAL;
  cvt_all_kernel<<<(WC_TOTAL + 255) / 256, 256, 0, stream>>>(ca, wc, flag);
  build_bfrag<<<(9216 + 255) / 256, 256, 0, stream>>>(wc + W_FULL_O, wbf);
  if (full) bond_prep<<<NSUP, 256, 0, stream>>>(nbr_fea, bpad, flag);

  embed_kernel<<<NATOM / 4, 256, 0, stream>>>(atom_fea, wc + W_EMB_O, wc + B_EMB_O,
                                              x, xh, flag);
  const int LDS_STATS_P = 2 * 128 * 4;                          // 1024
  const int LDS_ACT_P   = (48 * GS + 4 * 64 + 2 * 64) * 4;      // 26880
  const int LDS_STATS_F = 6144 + 2 * 128 * 4;                   // 7168
  const int LDS_ACT_F   = 6144 + (48 * GS + 128) * 4;           // 32000
  for (int i = 0; i < 3; i++){
    const u16* wbf_l = wbf + (size_t)i * 3072 * 8;
    hipMemsetAsync(sum1, 0, 384 * sizeof(float), stream);
    if (full){
      conv_pipe8<0><<<CGRID, 512, LDS_STATS_P, stream>>>(xh, bpad, nbr_idx,
          wbf_l, wc + B_FULL_O + i * F2D, sum1, sq1, wc + G1_O + i * F2D,
          wc + BE1_O + i * F2D, summed, sum1, sq1);
      conv_pipe8<1><<<CGRID, 512, LDS_ACT_P, stream>>>(xh, bpad, nbr_idx,
          wbf_l, wc + B_FULL_O + i * F2D, sum1, sq1, wc + G1_O + i * F2D,
          wc + BE1_O + i * F2D, summed, sum2, sq2);
    } else {
      conv_mfma<0><<<CGRID, 256, LDS_STATS_F, stream>>>(xh, nbr_fea, nbr_idx,
          wbf_l, wc + B_FULL_O + i * F2D, sum1, sq1, wc + G1_O + i * F2D,
          wc + BE1_O + i * F2D, summed, sum1, sq1, flag);
      conv_mfma<1><<<CGRID, 256, LDS_ACT_F, stream>>>(xh, nbr_fea, nbr_idx,
          wbf_l, wc + B_FULL_O + i * F2D, sum1, sq1, wc + G1_O + i * F2D,
          wc + BE1_O + i * F2D, summed, sum2, sq2, flag);
    }
    update_x_kernel<<<(NATOM * FD) / 256, 256, 0, stream>>>(x, xh, summed, sum2, sq2,
        wc + G2_O + i * FD, wc + BE2_O + i * FD);
  }
  hipMemsetAsync(crys, 0, (NCRY * FD + NCRY) * sizeof(float), stream);
  pool_kernel<<<(NATOM * FD) / 256, 256, 0, stream>>>(x, cidx, crys, cnt);
  head_kernel<<<NCRY, 128, 0, stream>>>(crys, cnt, wc + W_FC_O, wc + B_FC_O,
      wc + W_OUT_O, wc + B_OUT_O, d_out, flag);
}

// Round 5
// 1073.627 us; speedup vs baseline: 1.2654x; 1.2654x over previous
//
#include <hip/hip_runtime.h>
#include <hip/hip_bf16.h>

// CGCNN forward, MFMA conv GEMM (R13).
//   g[e,:] = [x[n(e)] | x[nb(e)] | bond(e)] @ Wf + b  (K=169 pad 192, N=128)
// R13 vs R12: hipcc's allocator targets MAX occupancy and spills prefetch
// state (R9/R10/R11/R12 all hit it; launch_bounds min-waves can't stop it).
// Fix: __attribute__((amdgpu_waves_per_eu(3,4))) pins the occupancy target
// so ~115 live VGPRs fit without spill. Structure (back to R8's 256-thr,
// 4-wave, 2 N-tiles/wave shape):
//   - bond_pad (the HBM-latency stream, block-uniform & linear) staged via
//     global_load_lds DMA, double-buffered: zero VGPR cost, one full
//     iteration of slack. Fragment-major layout (R10-verified).
//   - xh gathers (L2-resident) stay direct per-lane, et-group-pipelined one
//     group ahead (rolling X[2] sets, full unroll -> static indexing).
//   - nbr indices prefetched 2 supertiles deep.
//   - NO sched_barrier in the MFMA stream (R12 lesson / m141).
//   - one __syncthreads per supertile (drains DMA; it had the whole iter);
//     ACT mid-barrier is lgkm-only raw s_barrier (R11-verified).
// Canary: VGPR 100-128, stats WRITE ~1MB. If VGPR<100 & WRITE high, the
// allocator won again.
// R7 LDS-staging fallback kept for ws_size < 108.5 MB.

#define NATOM 60000
#define MNBR  12
#define F0D   92
#define FBD   41
#define FD    64
#define F2D   128
#define NCRY  2000
#define HD    128
#define NSUP  15000          // 720000 edges / 48
#define GS    132            // gbuf row stride (floats)
#define CGRID 3000           // conv grid; NSUP/CGRID == 5 exactly

// ws layout (float units)
#define OFF_X      0ull          // 3,840,000 f32
#define OFF_XH     3840000ull    // 3,840,000 u16
#define OFF_SUMMED 5760000ull    // 3,840,000 f32
#define OFF_STATS  9600000ull    // sum1[128] sq1[128] sum2[64] sq2[64]
#define OFF_CRYS   9600384ull
#define OFF_CNT    9728384ull
#define OFF_WCONV  9730384ull    // 80,833 f32
#define OFF_WBF    9811220ull    // 73,728 u16 = 36,864 f slots
#define OFF_FLAG   9848084ull
#define WS_NEED_BYTES (9848085ull * 4ull)
#define OFF_BPAD   9848088ull    // 34,560,000 u16 = 17,280,000 f slots (16B aligned)
#define WS_FULL_BYTES ((OFF_BPAD + 17280000ull) * 4ull)   // 108,512,352

// offsets inside wconv
#define W_EMB_O  0
#define B_EMB_O  5888
#define W_FULL_O 5952
#define B_FULL_O 70848
#define G1_O     71232
#define BE1_O    71616
#define G2_O     72000
#define BE2_O    72192
#define W_FC_O   72384
#define B_FC_O   80576
#define W_OUT_O  80704
#define B_OUT_O  80832
#define WC_TOTAL 80833

typedef unsigned short u16;
typedef __attribute__((ext_vector_type(8))) short bf16x8;
typedef __attribute__((ext_vector_type(4))) float f32x4;

__device__ __forceinline__ float bf2f(u16 u){
  union { unsigned int i; float f; } v; v.i = ((unsigned int)u) << 16; return v.f;
}
__device__ __forceinline__ u16 f2bf(float f){
  union { float f; unsigned int i; } v; v.f = f;
  unsigned int x = v.i;
  return (u16)((x + 0x7FFFu + ((x >> 16) & 1u)) >> 16);
}
__device__ __forceinline__ float softplusf_(float x){
  return fmaxf(x, 0.f) + log1pf(expf(-fabsf(x)));
}
__device__ __forceinline__ float softplus_fast(float x){
  return fmaxf(x, 0.f) + __logf(1.f + __expf(-fabsf(x)));
}
__device__ __forceinline__ float sigmoid_fast(float x){
  return __builtin_amdgcn_rcpf(1.f + __expf(-x));
}

// async global->LDS DMA, 16B per lane. LDS dest = wave-uniform base + lane*16.
typedef const __attribute__((address_space(1))) unsigned int* gup;
typedef __attribute__((address_space(3))) unsigned int* lup;
__device__ __forceinline__ void dma16(const void* g, void* l){
  __builtin_amdgcn_global_load_lds((gup)g, (lup)l, 16, 0, 0);
}

__global__ __launch_bounds__(64) void detect_kernel(
    const u16* __restrict__ data, int* __restrict__ flag){
  int tid = threadIdx.x;
  float v = bf2f(data[tid * 2]);
  float av = fabsf(v);
  bool sane = (av > 1e-6f) && (av < 100.f);
  unsigned long long m = __ballot(sane);
  if (tid == 0) *flag = (__popcll(m) >= 32) ? 1 : 0;
}

struct CvtArgs {
  const void* src[12];
  int start[13];
};

__global__ __launch_bounds__(256) void cvt_all_kernel(
    CvtArgs a, float* __restrict__ dst, const int* __restrict__ flag){
  int i = blockIdx.x * 256 + threadIdx.x;
  if (i >= WC_TOTAL) return;
  int r = 0;
  while (i >= a.start[r + 1]) r++;
  int rel = i - a.start[r];
  if (*flag) dst[i] = bf2f(((const u16*)a.src[r])[rel]);
  else       dst[i] = ((const float*)a.src[r])[rel];
}

__global__ __launch_bounds__(256) void build_bfrag(
    const float* __restrict__ wfull, u16* __restrict__ wbf){
  int t = blockIdx.x * 256 + threadIdx.x;
  if (t >= 3 * 6 * 8 * 64) return;
  int lane = t & 63, nt = (t >> 6) & 7, c = (t >> 9) % 6, layer = t / 3072;
  int q = lane >> 4, nloc = lane & 15;
  u16 vals[8];
  #pragma unroll
  for (int i = 0; i < 8; i++){
    int k = c * 32 + q * 8 + i;
    float v = (k < 169) ? wfull[layer * 169 * F2D + k * F2D + nt * 16 + nloc] : 0.f;
    vals[i] = f2bf(v);
  }
  *(uint4*)&wbf[(size_t)t * 8] = *(uint4*)vals;
}

// One-time repack, FRAGMENT-MAJOR per supertile (288 16B slots, R10-verified):
//   slot j: et=j/96, jj=j%96
//     jj<64 : chunk4 — lane=jj, row=et*16+(lane&15), feats (lane>>4)*8..+7
//     jj>=64: chunk5 — l2=jj-64, row=et*16+(l2&15), feats 32+(l2>>4)*8..+7
__global__ __launch_bounds__(256) void bond_prep(
    const void* __restrict__ nbr_fea, u16* __restrict__ bond_pad,
    const int* __restrict__ flag){
  __shared__ __align__(16) char sm[7872];
  u16*   lb_u = (u16*)sm;
  float* lb_f = (float*)sm;
  int s = blockIdx.x, tid = threadIdx.x;
  const int isbf = *flag;
  if (isbf){
    const uint4* src = (const uint4*)((const u16*)nbr_fea + (size_t)s * 1968);
    if (tid < 246) ((uint4*)sm)[tid] = src[tid];
  } else {
    const uint4* src = (const uint4*)((const float*)nbr_fea + (size_t)s * 1968);
    for (int t = tid; t < 492; t += 256) ((uint4*)sm)[t] = src[t];
  }
  __syncthreads();
  uint4* outv = (uint4*)(bond_pad + (size_t)s * 2304);
  for (int slot = tid; slot < 288; slot += 256){
    int et = slot / 96, jj = slot - et * 96;
    int l  = (jj < 64) ? jj : (jj - 64);
    int row = et * 16 + (l & 15);
    int kb  = ((jj < 64) ? 0 : 32) + (l >> 4) * 8;
    u16 v[8];
    #pragma unroll
    for (int i = 0; i < 8; i++){
      int k = kb + i;
      v[i] = (k < FBD) ? (isbf ? lb_u[row * FBD + k] : f2bf(lb_f[row * FBD + k])) : (u16)0;
    }
    outv[slot] = *(uint4*)v;
  }
}

__global__ __launch_bounds__(256) void embed_kernel(
    const void* __restrict__ atom_fea, const float* __restrict__ W_emb,
    const float* __restrict__ b_emb, float* __restrict__ x,
    u16* __restrict__ xh, const int* __restrict__ flag){
  int tid = threadIdx.x;
  int n = blockIdx.x * 4 + (tid >> 6);
  int f = tid & 63;
  float acc = b_emb[f];
  if (*flag){
    const u16* arow = (const u16*)atom_fea + n * F0D;
    for (int k = 0; k < F0D; k++)
      acc = fmaf(bf2f(arow[k]), W_emb[k * FD + f], acc);
  } else {
    const float* arow = (const float*)atom_fea + n * F0D;
    for (int k = 0; k < F0D; k++)
      acc = fmaf(arow[k], W_emb[k * FD + f], acc);
  }
  x[n * FD + f] = acc;
  xh[n * FD + f] = f2bf(acc);
}

// ---------------------------------------------------------------------------
// R13: bond-DMA + et-pipelined conv pass. 256 thr, 4 waves, wave w owns
// N-cols [w*32, w*32+32) as two 16-col t2 tiles (R8 shape).
// LDS: [0,9216) bond double-buffer (2x4608, fragment-major);
//      ACT: gbuf 48*GS f32 at 9216, then redS/redQ(64+64).
//      stats: redS/redQ(128+128) at 9216.
// ---------------------------------------------------------------------------
template<int ACT>
__global__ __launch_bounds__(256)
__attribute__((amdgpu_waves_per_eu(3, 4)))
void conv_dma(
    const u16* __restrict__ xh, const u16* __restrict__ bond_pad,
    const int* __restrict__ nbr_idx, const u16* __restrict__ wbf_l,
    const float* __restrict__ bfull, const float* __restrict__ sum1,
    const float* __restrict__ sq1, const float* __restrict__ g1,
    const float* __restrict__ be1, float* __restrict__ summed,
    float* __restrict__ o_sum, float* __restrict__ o_sq){
  extern __shared__ char smem[];
  char* stg  = smem;                                  // 2 x 4608
  float* gbuf = (float*)(smem + 9216);                // ACT only
  float* redS = ACT ? (float*)(smem + 9216 + 48 * GS * 4)
                    : (float*)(smem + 9216);
  float* redQ = redS + (ACT ? 64 : 128);

  const int tid = threadIdx.x;
  const int w = tid >> 6, lane = tid & 63;
  const int q = lane >> 4, nloc = lane & 15;

  bf16x8 Bf[6][2];
  const bf16x8* Bv = (const bf16x8*)wbf_l;
  #pragma unroll
  for (int c = 0; c < 6; c++)
    #pragma unroll
    for (int t2 = 0; t2 < 2; t2++)
      Bf[c][t2] = Bv[(c * 8 + w * 2 + t2) * 64 + lane];
  float bias0 = bfull[w * 32 + nloc];
  float bias1 = bfull[w * 32 + 16 + nloc];

  float A0 = 0.f, B0 = 0.f, A1 = 0.f, B1 = 0.f;
  if (ACT){
    const float invR = 1.f / (float)(NATOM * MNBR);
    float m0 = sum1[lane] * invR;
    float v0 = fmaxf(sq1[lane] * invR - m0 * m0, 0.f);
    A0 = g1[lane] * rsqrtf(v0 + 1e-5f);  B0 = be1[lane] - m0 * A0;
    float m1 = sum1[64 + lane] * invR;
    float v1 = fmaxf(sq1[64 + lane] * invR - m1 * m1, 0.f);
    A1 = g1[64 + lane] * rsqrtf(v1 + 1e-5f);  B1 = be1[64 + lane] - m1 * A1;
  }
  float sAcc0 = 0.f, sAcc1 = 0.f, qAcc0 = 0.f, qAcc1 = 0.f;
  if (tid < (ACT ? 64 : 128)){ redS[tid] = 0.f; redQ[tid] = 0.f; }

  const bf16x8* xv = (const bf16x8*)xh;
  const char* bpad8 = (const char*)bond_pad;
  const bf16x8 zero8 = {0,0,0,0,0,0,0,0};
  const int s0 = blockIdx.x;

#define STAGE_BOND(DST, SS) {                                                   \
    const char* gsrc_ = bpad8 + (size_t)(SS) * 4608;                            \
    dma16(gsrc_ + (size_t)tid * 16, (DST) + w * 1024);                          \
    if (tid < 32) dma16(gsrc_ + 4096 + (size_t)tid * 16, (DST) + 4096);         \
  }
#define LOADX(P, SS, ET, NB) {                                                  \
    int na_ = (SS) * 4 + ((ET) * 16 + nloc) / 12;                               \
    P[0] = xv[(size_t)na_ * 8 + q];                                             \
    P[1] = xv[(size_t)na_ * 8 + 4 + q];                                         \
    P[2] = xv[(size_t)(NB) * 8 + q];                                            \
    P[3] = xv[(size_t)(NB) * 8 + 4 + q];                                        \
  }
#define MFMA_G(P, CB, ET, SS) {                                                 \
    bf16x8 a4_ = *(const bf16x8*)((CB) + ((ET) * 96 + lane) * 16);              \
    bf16x8 a5_ = (lane < 32)                                                    \
        ? *(const bf16x8*)((CB) + ((ET) * 96 + 64 + lane) * 16) : zero8;        \
    _Pragma("unroll")                                                           \
    for (int t2 = 0; t2 < 2; t2++){                                             \
      float bs_ = t2 ? bias1 : bias0;                                           \
      f32x4 acc = {bs_, bs_, bs_, bs_};                                         \
      acc = __builtin_amdgcn_mfma_f32_16x16x32_bf16(a4_, Bf[4][t2], acc, 0,0,0);\
      acc = __builtin_amdgcn_mfma_f32_16x16x32_bf16(a5_, Bf[5][t2], acc, 0,0,0);\
      acc = __builtin_amdgcn_mfma_f32_16x16x32_bf16(P[0], Bf[0][t2], acc, 0,0,0);\
      acc = __builtin_amdgcn_mfma_f32_16x16x32_bf16(P[1], Bf[1][t2], acc, 0,0,0);\
      acc = __builtin_amdgcn_mfma_f32_16x16x32_bf16(P[2], Bf[2][t2], acc, 0,0,0);\
      acc = __builtin_amdgcn_mfma_f32_16x16x32_bf16(P[3], Bf[3][t2], acc, 0,0,0);\
      if (ACT){                                                                 \
        int col_ = w * 32 + t2 * 16 + nloc;                                     \
        int r0_ = (ET) * 16 + q * 4;                                            \
        gbuf[(r0_ + 0) * GS + col_] = acc[0];                                   \
        gbuf[(r0_ + 1) * GS + col_] = acc[1];                                   \
        gbuf[(r0_ + 2) * GS + col_] = acc[2];                                   \
        gbuf[(r0_ + 3) * GS + col_] = acc[3];                                   \
      } else {                                                                  \
        float ss_ = acc[0] + acc[1] + acc[2] + acc[3];                          \
        float qq_ = acc[0]*acc[0] + acc[1]*acc[1] + acc[2]*acc[2] + acc[3]*acc[3];\
        if (t2){ sAcc1 += ss_; qAcc1 += qq_; } else { sAcc0 += ss_; qAcc0 += qq_; }\
      }                                                                         \
    }                                                                           \
  }

  // prologue: indices 2 deep, bond DMA for s0, et0 xh frags
  int nbc[3], nbn[3];
  #pragma unroll
  for (int et = 0; et < 3; et++) nbc[et] = nbr_idx[s0 * 48 + et * 16 + nloc];
  #pragma unroll
  for (int et = 0; et < 3; et++)
    nbn[et] = nbr_idx[(s0 + CGRID) * 48 + et * 16 + nloc];
  STAGE_BOND(stg, s0);
  bf16x8 X[2][4];
  LOADX(X[0], s0, 0, nbc[0]);
  __syncthreads();   // drains DMA(s0) + idx + X0 loads; buf0 ready

  #pragma unroll
  for (int k = 0; k < 5; k++){
    const int s = s0 + k * CGRID;
    char* cb   = stg + (k & 1) * 4608;
    char* nbuf = stg + ((k & 1) ^ 1) * 4608;
    if (k < 4) STAGE_BOND(nbuf, s + CGRID);           // lands under this iter
    LOADX(X[(3*k + 1) & 1], s, 1, nbc[1]);
    MFMA_G(X[(3*k) & 1], cb, 0, s);
    LOADX(X[(3*k + 2) & 1], s, 2, nbc[2]);
    MFMA_G(X[(3*k + 1) & 1], cb, 1, s);
    if (k < 4) LOADX(X[(3*k + 3) & 1], s + CGRID, 0, nbn[0]);
    MFMA_G(X[(3*k + 2) & 1], cb, 2, s);
    if (k < 4){
      nbc[0] = nbn[0]; nbc[1] = nbn[1]; nbc[2] = nbn[2];
      if (k < 3){
        #pragma unroll
        for (int et = 0; et < 3; et++)
          nbn[et] = nbr_idx[(s + 2 * CGRID) * 48 + et * 16 + nloc];
      }
    }
    if (ACT){
      // gbuf complete: LDS-only drain + raw barrier (global prefetch for
      // s+1 stays in flight under the ACT phase)
      __builtin_amdgcn_sched_barrier(0);
      asm volatile("s_waitcnt lgkmcnt(0)");
      __builtin_amdgcn_s_barrier();
      __builtin_amdgcn_sched_barrier(0);
      float p = 0.f;
      #pragma unroll
      for (int m = 0; m < 12; m++){
        int el = w * 12 + m;
        float u = fmaf(gbuf[el * GS + lane],      A0, B0);
        float v = fmaf(gbuf[el * GS + 64 + lane], A1, B1);
        p = fmaf(sigmoid_fast(u), softplus_fast(v), p);
      }
      summed[((size_t)s * 4 + w) * 64 + lane] = p;
      sAcc0 += p;  qAcc0 = fmaf(p, p, qAcc0);
    }
    // end of supertile: full drain (DMA for s+1 done; gbuf/bond reusable)
    __syncthreads();
  }
#undef STAGE_BOND
#undef LOADX
#undef MFMA_G

  if (ACT){
    atomicAdd(&redS[lane], sAcc0);
    atomicAdd(&redQ[lane], qAcc0);
    __syncthreads();
    if (tid < 64){ atomicAdd(&o_sum[tid], redS[tid]); atomicAdd(&o_sq[tid], redQ[tid]); }
  } else {
    int c0 = w * 32 + nloc;
    atomicAdd(&redS[c0], sAcc0);       atomicAdd(&redQ[c0], qAcc0);
    atomicAdd(&redS[c0 + 16], sAcc1);  atomicAdd(&redQ[c0 + 16], qAcc1);
    __syncthreads();
    if (tid < 128){ atomicAdd(&o_sum[tid], redS[tid]); atomicAdd(&o_sq[tid], redQ[tid]); }
  }
}

// R7 fallback conv pass (small-ws path; reads raw nbr_fea, no bond_pad).
template<int ACT>
__global__ __launch_bounds__(256, 3) void conv_mfma(
    const u16* __restrict__ xh, const void* __restrict__ nbr_fea,
    const int* __restrict__ nbr_idx, const u16* __restrict__ wbf_l,
    const float* __restrict__ bfull, const float* __restrict__ sum1,
    const float* __restrict__ sq1, const float* __restrict__ g1,
    const float* __restrict__ be1, float* __restrict__ summed,
    float* __restrict__ o_sum, float* __restrict__ o_sq,
    const int* __restrict__ flag){
  extern __shared__ char smem[];
  u16*   fragA = (u16*)smem;                      // 6*512 u16
  float* gbuf  = (float*)(smem + 6144);           // ACT only: 48*GS
  float* redS  = ACT ? (gbuf + 48 * GS) : (float*)(smem + 6144);
  float* redQ  = redS + (ACT ? 64 : 128);

  const int tid = threadIdx.x;
  const int w = tid >> 6, lane = tid & 63;
  const int q = lane >> 4, nloc = lane & 15, q8 = q * 8;
  const int isbf = *flag;

  bf16x8 Bf[6][2];
  const bf16x8* Bv = (const bf16x8*)wbf_l;
  #pragma unroll
  for (int c = 0; c < 6; c++)
    #pragma unroll
    for (int t2 = 0; t2 < 2; t2++)
      Bf[c][t2] = Bv[(c * 8 + w * 2 + t2) * 64 + lane];
  float bias0 = bfull[w * 32 + nloc];
  float bias1 = bfull[w * 32 + 16 + nloc];

  float A0 = 0.f, B0 = 0.f, A1 = 0.f, B1 = 0.f;
  if (ACT){
    const float invR = 1.f / (float)(NATOM * MNBR);
    float m0 = sum1[lane] * invR;
    float v0 = fmaxf(sq1[lane] * invR - m0 * m0, 0.f);
    A0 = g1[lane] * rsqrtf(v0 + 1e-5f);  B0 = be1[lane] - m0 * A0;
    float m1 = sum1[64 + lane] * invR;
    float v1 = fmaxf(sq1[64 + lane] * invR - m1 * m1, 0.f);
    A1 = g1[64 + lane] * rsqrtf(v1 + 1e-5f);  B1 = be1[64 + lane] - m1 * A1;
  }
  float sAcc0 = 0.f, sAcc1 = 0.f, qAcc0 = 0.f, qAcc1 = 0.f;
  if (tid < (ACT ? 64 : 128)){ redS[tid] = 0.f; redQ[tid] = 0.f; }

  const bf16x8* xv = (const bf16x8*)xh;
  for (int s = blockIdx.x; s < NSUP; s += gridDim.x){
    int e0 = s * 48 + nloc;
    int nb0 = nbr_idx[e0], nb1 = nbr_idx[e0 + 16], nb2 = nbr_idx[e0 + 32];
    bf16x8 Af[3][6];
    if (w < 3){
      size_t eg = (size_t)(s * 48 + w * 16 + nloc);
      u16 v4[8], v5[8];
      if (isbf){
        const u16* br = (const u16*)nbr_fea + eg * 41;
        #pragma unroll
        for (int i = 0; i < 8; i++) v4[i] = br[q8 + i];
        #pragma unroll
        for (int i = 0; i < 8; i++){
          int k5 = 32 + q8 + i;
          v5[i] = (k5 < 41) ? br[k5] : (u16)0;
        }
      } else {
        const float* br = (const float*)nbr_fea + eg * 41;
        #pragma unroll
        for (int i = 0; i < 8; i++) v4[i] = f2bf(br[q8 + i]);
        #pragma unroll
        for (int i = 0; i < 8; i++){
          int k5 = 32 + q8 + i;
          v5[i] = (k5 < 41) ? f2bf(br[k5]) : (u16)0;
        }
      }
      *(uint4*)&fragA[(w * 2 + 0) * 512 + lane * 8] = *(uint4*)v4;
      *(uint4*)&fragA[(w * 2 + 1) * 512 + lane * 8] = *(uint4*)v5;
    }
    __syncthreads();
    #pragma unroll
    for (int et = 0; et < 3; et++){
      int nb = (et == 0) ? nb0 : (et == 1) ? nb1 : nb2;
      int na = s * 4 + (et * 16 + nloc) / 12;
      Af[et][0] = xv[na * 8 + q];
      Af[et][1] = xv[na * 8 + 4 + q];
      Af[et][2] = xv[nb * 8 + q];
      Af[et][3] = xv[nb * 8 + 4 + q];
      Af[et][4] = *(bf16x8*)&fragA[(et * 2 + 0) * 512 + lane * 8];
      Af[et][5] = *(bf16x8*)&fragA[(et * 2 + 1) * 512 + lane * 8];
    }
    #pragma unroll
    for (int et = 0; et < 3; et++){
      #pragma unroll
      for (int t2 = 0; t2 < 2; t2++){
        float bs = t2 ? bias1 : bias0;
        f32x4 acc = {bs, bs, bs, bs};
        acc = __builtin_amdgcn_mfma_f32_16x16x32_bf16(Af[et][0], Bf[0][t2], acc, 0, 0, 0);
        acc = __builtin_amdgcn_mfma_f32_16x16x32_bf16(Af[et][1], Bf[1][t2], acc, 0, 0, 0);
        acc = __builtin_amdgcn_mfma_f32_16x16x32_bf16(Af[et][2], Bf[2][t2], acc, 0, 0, 0);
        acc = __builtin_amdgcn_mfma_f32_16x16x32_bf16(Af[et][3], Bf[3][t2], acc, 0, 0, 0);
        acc = __builtin_amdgcn_mfma_f32_16x16x32_bf16(Af[et][4], Bf[4][t2], acc, 0, 0, 0);
        acc = __builtin_amdgcn_mfma_f32_16x16x32_bf16(Af[et][5], Bf[5][t2], acc, 0, 0, 0);
        if (ACT){
          int col = w * 32 + t2 * 16 + nloc;
          int r0 = et * 16 + q * 4;
          gbuf[(r0 + 0) * GS + col] = acc[0];
          gbuf[(r0 + 1) * GS + col] = acc[1];
          gbuf[(r0 + 2) * GS + col] = acc[2];
          gbuf[(r0 + 3) * GS + col] = acc[3];
        } else {
          float ss = acc[0] + acc[1] + acc[2] + acc[3];
          float qq = acc[0]*acc[0] + acc[1]*acc[1] + acc[2]*acc[2] + acc[3]*acc[3];
          if (t2){ sAcc1 += ss; qAcc1 += qq; } else { sAcc0 += ss; qAcc0 += qq; }
        }
      }
    }
    if (ACT){
      __syncthreads();
      float p = 0.f;
      #pragma unroll
      for (int m = 0; m < 12; m++){
        int el = w * 12 + m;
        float u = fmaf(gbuf[el * GS + lane],      A0, B0);
        float v = fmaf(gbuf[el * GS + 64 + lane], A1, B1);
        p = fmaf(sigmoid_fast(u), softplus_fast(v), p);
      }
      summed[(s * 4 + w) * 64 + lane] = p;
      sAcc0 += p;  qAcc0 = fmaf(p, p, qAcc0);
    }
    __syncthreads();
  }
  if (ACT){
    atomicAdd(&redS[lane], sAcc0);
    atomicAdd(&redQ[lane], qAcc0);
    __syncthreads();
    if (tid < 64){ atomicAdd(&o_sum[tid], redS[tid]); atomicAdd(&o_sq[tid], redQ[tid]); }
  } else {
    int c0 = w * 32 + nloc;
    atomicAdd(&redS[c0], sAcc0);       atomicAdd(&redQ[c0], qAcc0);
    atomicAdd(&redS[c0 + 16], sAcc1);  atomicAdd(&redQ[c0 + 16], qAcc1);
    __syncthreads();
    if (tid < 128){ atomicAdd(&o_sum[tid], redS[tid]); atomicAdd(&o_sq[tid], redQ[tid]); }
  }
}

__global__ __launch_bounds__(256) void update_x_kernel(
    float* __restrict__ x, u16* __restrict__ xh,
    const float* __restrict__ summed,
    const float* __restrict__ sum2, const float* __restrict__ sq2,
    const float* __restrict__ g2, const float* __restrict__ be2){
  int idx = blockIdx.x * 256 + threadIdx.x;
  int f = idx & 63;
  const float invN = 1.f / (float)NATOM;
  float mean = sum2[f] * invN;
  float var  = fmaxf(sq2[f] * invN - mean * mean, 0.f);
  float a = g2[f] * rsqrtf(var + 1e-5f);
  float b = be2[f] - mean * a;
  float v = x[idx] + fmaf(summed[idx], a, b);
  float r = softplusf_(v);
  x[idx] = r;
  xh[idx] = f2bf(r);
}

__global__ __launch_bounds__(256) void pool_kernel(
    const float* __restrict__ x, const int* __restrict__ cidx,
    float* __restrict__ crys, float* __restrict__ cnt){
  int idx = blockIdx.x * 256 + threadIdx.x;
  int n = idx >> 6, f = idx & 63;
  int c = cidx[n];
  atomicAdd(&crys[c * FD + f], x[idx]);
  if (f == 0) atomicAdd(&cnt[c], 1.f);
}

__global__ __launch_bounds__(128) void head_kernel(
    const float* __restrict__ crys, const float* __restrict__ cnt,
    const float* __restrict__ W_fc, const float* __restrict__ b_fc,
    const float* __restrict__ W_out, const float* __restrict__ b_out,
    void* __restrict__ out, const int* __restrict__ flag){
  __shared__ float p_s[FD];
  __shared__ float red_s[HD];
  int c = blockIdx.x, tid = threadIdx.x;
  if (tid < FD){
    float ct = fmaxf(cnt[c], 1.f);
    p_s[tid] = softplusf_(crys[c * FD + tid] / ct);
  }
  __syncthreads();
  float acc = b_fc[tid];
  for (int k = 0; k < FD; k++)
    acc = fmaf(p_s[k], W_fc[k * HD + tid], acc);
  float h = softplusf_(acc);
  red_s[tid] = h * W_out[tid];
  __syncthreads();
  for (int s = HD / 2; s > 0; s >>= 1){
    if (tid < s) red_s[tid] += red_s[tid + s];
    __syncthreads();
  }
  if (tid == 0){
    float r = red_s[0] + b_out[0];
    if (*flag) ((u16*)out)[c] = f2bf(r);
    else       ((float*)out)[c] = r;
  }
}

extern "C" void kernel_launch(void* const* d_in, const int* in_sizes, int n_in,
                              void* d_out, int out_size, void* d_ws, size_t ws_size,
                              hipStream_t stream){
  if (ws_size < WS_NEED_BYTES) return;  // diagnostic: leaves d_out zeroed
  const bool full = (ws_size >= WS_FULL_BYTES);
  const void* atom_fea = d_in[0];
  const void* nbr_fea  = d_in[1];
  const int* nbr_idx   = (const int*)d_in[2];
  const int* cidx      = (const int*)d_in[3];

  float* ws     = (float*)d_ws;
  float* x      = ws + OFF_X;
  u16*   xh     = (u16*)(ws + OFF_XH);
  float* summed = ws + OFF_SUMMED;
  float* sum1   = ws + OFF_STATS;
  float* sq1    = sum1 + 128;
  float* sum2   = sq1 + 128;
  float* sq2    = sum2 + 64;
  float* crys   = ws + OFF_CRYS;
  float* cnt    = ws + OFF_CNT;
  float* wc     = ws + OFF_WCONV;
  u16*   wbf    = (u16*)(ws + OFF_WBF);
  int*   flag   = (int*)(ws + OFF_FLAG);
  u16*   bpad   = (u16*)(ws + OFF_BPAD);

  detect_kernel<<<1, 64, 0, stream>>>((const u16*)nbr_fea, flag);
  CvtArgs ca;
  const int srcidx[12] = {4,5,6,7,8,9,10,11,12,13,14,15};
  const int starts[13] = {W_EMB_O, B_EMB_O, W_FULL_O, B_FULL_O, G1_O, BE1_O,
                          G2_O, BE2_O, W_FC_O, B_FC_O, W_OUT_O, B_OUT_O, WC_TOTAL};
  for (int i = 0; i < 12; i++){ ca.src[i] = d_in[srcidx[i]]; ca.start[i] = starts[i]; }
  ca.start[12] = WC_TOTAL;
  cvt_all_kernel<<<(WC_TOTAL + 255) / 256, 256, 0, stream>>>(ca, wc, flag);
  build_bfrag<<<(9216 + 255) / 256, 256, 0, stream>>>(wc + W_FULL_O, wbf);
  if (full) bond_prep<<<NSUP, 256, 0, stream>>>(nbr_fea, bpad, flag);

  embed_kernel<<<NATOM / 4, 256, 0, stream>>>(atom_fea, wc + W_EMB_O, wc + B_EMB_O,
                                              x, xh, flag);
  const int LDS_STATS_D = 9216 + 2 * 128 * 4;                   // 10240
  const int LDS_ACT_D   = 9216 + 48 * GS * 4 + 2 * 64 * 4;      // 35072
  const int LDS_STATS_F = 6144 + 2 * 128 * 4;                   // 7168
  const int LDS_ACT_F   = 6144 + (48 * GS + 128) * 4;           // 32000
  for (int i = 0; i < 3; i++){
    const u16* wbf_l = wbf + (size_t)i * 3072 * 8;
    hipMemsetAsync(sum1, 0, 384 * sizeof(float), stream);
    if (full){
      conv_dma<0><<<CGRID, 256, LDS_STATS_D, stream>>>(xh, bpad, nbr_idx,
          wbf_l, wc + B_FULL_O + i * F2D, sum1, sq1, wc + G1_O + i * F2D,
          wc + BE1_O + i * F2D, summed, sum1, sq1);
      conv_dma<1><<<CGRID, 256, LDS_ACT_D, stream>>>(xh, bpad, nbr_idx,
          wbf_l, wc + B_FULL_O + i * F2D, sum1, sq1, wc + G1_O + i * F2D,
          wc + BE1_O + i * F2D, summed, sum2, sq2);
    } else {
      conv_mfma<0><<<CGRID, 256, LDS_STATS_F, stream>>>(xh, nbr_fea, nbr_idx,
          wbf_l, wc + B_FULL_O + i * F2D, sum1, sq1, wc + G1_O + i * F2D,
          wc + BE1_O + i * F2D, summed, sum1, sq1, flag);
      conv_mfma<1><<<CGRID, 256, LDS_ACT_F, stream>>>(xh, nbr_fea, nbr_idx,
          wbf_l, wc + B_FULL_O + i * F2D, sum1, sq1, wc + G1_O + i * F2D,
          wc + BE1_O + i * F2D, summed, sum2, sq2, flag);
    }
    update_x_kernel<<<(NATOM * FD) / 256, 256, 0, stream>>>(x, xh, summed, sum2, sq2,
        wc + G2_O + i * FD, wc + BE2_O + i * FD);
  }
  hipMemsetAsync(crys, 0, (NCRY * FD + NCRY) * sizeof(float), stream);
  pool_kernel<<<(NATOM * FD) / 256, 256, 0, stream>>>(x, cidx, crys, cnt);
  head_kernel<<<NCRY, 128, 0, stream>>>(crys, cnt, wc + W_FC_O, wc + B_FC_O,
      wc + W_OUT_O, wc + B_OUT_O, d_out, flag);
}